// Round 21
// baseline (62.209 us; speedup 1.0000x reference)
//
#include <hip/hip_runtime.h>

#define HH 512
#define WW 512
#define HO 502
#define WO 502
#define KS 11
#define OTH 24                 // v-rows per tile (4 waves x 6)
#define RPT 6                  // v-rows per wave
#define NR  (RPT + KS - 1)     // 16 input rows per thread
#define OTW 40                 // output cols per tile
#define VW  50                 // v-cols = OTW + KS - 1
#define CSTR 25                // per-column stride in f32x2 (24 rows + 1, odd)
#define CPT 4                  // output cols per thread in phase 2 (10 groups x 4)
#define NPOS (CPT + KS - 1)    // 14 tap positions
#define NCG 10                 // active col groups (60 of 64 lanes)

#define NTX 13                 // x tiles (13*40 = 520 >= 502)
#define NTY 21                 // y tiles (21*24 = 504 >= 502)
#define NTILES (NTX * NTY)     // 273
#define NZ 48                  // B*C planes
#define TOTW (NTILES * NZ)     // 13104 tile-slices
#define NBLK 1792              // 7 blocks/CU x 256 CU
#define WQ (TOTW / NBLK)       // 7
#define WR (TOTW % NBLK)       // 560 blocks take one extra

typedef float f32x2 __attribute__((ext_vector_type(2)));

__device__ __forceinline__ float rfl(float x) {
    union { float f; int i; } u;
    u.f = x;
    u.i = __builtin_amdgcn_readfirstlane(u.i);
    return u.f;
}
__device__ __forceinline__ int rfli(int x) {
    return __builtin_amdgcn_readfirstlane(x);
}

// symmetric gaussian lookup, k compile-time
#define GW(k) g[(k) < 6 ? (k) : 10 - (k)]

__global__ __launch_bounds__(256)
void ssim_sep_kernel(
    const float* __restrict__ img1, const float* __restrict__ img2,
    const float* __restrict__ win, double* __restrict__ acc)
{
    // channel-paired intermediate: chp0 = {mu_s, mu_d}, chp1 = {E[s^2], E[d^2]}
    // Wave w exclusively owns v-rows [6w, 6w+6) -> no cross-wave deps, no barriers.
    __shared__ __align__(16) f32x2 vbuf2[2][VW][CSTR];   // 20,000 B -> 8 blocks/CU cap
    __shared__ float wsum[4];

    const int tid = threadIdx.x;
    const int bid = blockIdx.x;

    // 1-D gaussian (wave-uniform -> SGPRs): g[k] = w[5][k]/sqrt(w[5][5]); symmetric
    float g[6];
    {
        double inv = 1.0 / sqrt((double)win[5 * KS + 5]);
        #pragma unroll
        for (int k = 0; k < 6; ++k)
            g[k] = rfl((float)((double)win[5 * KS + k] * inv));
    }

    // ---- fixed per-thread roles ----
    const int lane = tid & 63;              // phase-1 v column
    const int wv   = tid >> 6;              // wave id 0..3
    const int j0   = rfli(wv * RPT);        // first v-row owned (wave-uniform SGPR)
    // phase-2 roles WITHIN-WAVE: 10 col-groups x 6 rows = 60 active lanes
    const int cg  = lane / 6;               // col group 0..10
    const int rl  = lane - 6 * cg;          // row within wave group 0..5
    const bool p2act = (cg < NCG);
    const int c0 = (p2act ? cg : NCG - 1) * CPT;  // clamp idle lanes in-bounds
    const int rowl = j0 + rl;               // local v-row for phase 2
    const float c1 = 1e-4f, c2 = 9e-4f;     // L = 1 for [0,1) inputs

    // ---- work chunk: contiguous [w0, w0+cnt) of 13104 tile-slices ----
    int w0, cnt;
    if (bid < WR) { w0 = bid * (WQ + 1);            cnt = WQ + 1; }
    else          { w0 = WR * (WQ + 1) + (bid - WR) * WQ; cnt = WQ; }
    w0 = rfli(w0); cnt = rfli(cnt);

    // one-time decomposition; block-uniform state pinned to SGPRs.
    int z   = rfli(w0 / NTILES);
    int rem = rfli(w0 % NTILES);
    int ty  = rfli(rem / NTX);
    int tx  = rfli(rem % NTX);
    int zoff = rfli(z * (HH * WW));
    int off0 = rfli(zoff + ty * (OTH * WW) + tx * OTW);
    int oy = rfli(ty * OTH), ox = rfli(tx * OTW);

    float a[NR], b[NR];

    // clamp-free fast path (interior tiles)
#define ISSUE_FAST()                                                  \
    {                                                                 \
        const float* pa_ = img1 + off0 + (j0 * WW) + lane;            \
        const float* pb_ = img2 + off0 + (j0 * WW) + lane;            \
        _Pragma("unroll")                                             \
        for (int ri = 0; ri < NR; ++ri) {                             \
            a[ri] = pa_[ri * WW];                                     \
            b[ri] = pb_[ri * WW];                                     \
        }                                                             \
    }
    // clamped path (edge tiles: tx==NTX-1 or ty==NTY-1)
#define ISSUE_EDGE()                                                  \
    {                                                                 \
        int gc_ = ox + lane; if (gc_ > WW - 1) gc_ = WW - 1;          \
        int r0_ = oy + j0;                                            \
        _Pragma("unroll")                                             \
        for (int ri = 0; ri < NR; ++ri) {                             \
            int gr_ = r0_ + ri; if (gr_ > HH - 1) gr_ = HH - 1;       \
            int ro_ = zoff + gr_ * WW + gc_;                          \
            a[ri] = img1[ro_];                                        \
            b[ri] = img2[ro_];                                        \
        }                                                             \
    }

    if (tx == NTX - 1 || ty == NTY - 1) { ISSUE_EDGE(); } else { ISSUE_FAST(); }

    float lsum = 0.f;

    for (int i = 0; i < cnt; ++i) {
        // ---------- phase 1, HALF A: rows j0..j0+2 (inputs 0..12) ----------
        // incremental s/d fold (2-reg temps), 3-row accumulators: VGPR <= 64
        {
            f32x2 mu[3], es[3];
            #pragma unroll
            for (int j = 0; j < 3; ++j) {
                mu[j] = (f32x2){0.f, 0.f};
                es[j] = (f32x2){0.f, 0.f};
            }
            #pragma unroll
            for (int ri = 0; ri < 13; ++ri) {
                f32x2 sv = {a[ri] + b[ri], a[ri] - b[ri]};
                f32x2 sq = sv * sv;         // pk_mul {s2, d2}
                #pragma unroll
                for (int j = 0; j < 3; ++j) {
                    int k = ri - j;
                    if (k >= 0 && k < KS) { // folds at compile time
                        float wk = GW(k);
                        mu[j] += wk * sv;   // pk_fma
                        es[j] += wk * sq;   // pk_fma
                    }
                }
            }
            if (lane < VW) {
                #pragma unroll
                for (int j = 0; j < 3; ++j) {
                    vbuf2[0][lane][j0 + j] = mu[j];
                    vbuf2[1][lane][j0 + j] = es[j];
                }
            }
        }
        // ---------- phase 1, HALF B: rows j0+3..j0+5 (inputs 3..15) ----------
        {
            f32x2 mu[3], es[3];
            #pragma unroll
            for (int j = 0; j < 3; ++j) {
                mu[j] = (f32x2){0.f, 0.f};
                es[j] = (f32x2){0.f, 0.f};
            }
            #pragma unroll
            for (int ri = 3; ri < NR; ++ri) {
                f32x2 sv = {a[ri] + b[ri], a[ri] - b[ri]};
                f32x2 sq = sv * sv;
                #pragma unroll
                for (int j = 0; j < 3; ++j) {
                    int k = ri - (j + 3);
                    if (k >= 0 && k < KS) { // folds at compile time
                        float wk = GW(k);
                        mu[j] += wk * sv;
                        es[j] += wk * sq;
                    }
                }
            }
            if (lane < VW) {
                #pragma unroll
                for (int j = 0; j < 3; ++j) {
                    vbuf2[0][lane][j0 + 3 + j] = mu[j];
                    vbuf2[1][lane][j0 + 3 + j] = es[j];
                }
            }
        }

        // snapshot current-item output coords (SGPR) for phase-2 masks
        const int oyc = rfli(oy), oxc = rfli(ox);

        // advance state incrementally (all SGPR) + issue next item's loads
        if (i + 1 < cnt) {
            tx = rfli(tx + 1); off0 = rfli(off0 + OTW); ox = rfli(ox + OTW);
            if (tx == NTX) {
                tx = 0; ox = 0;
                off0 = rfli(off0 + (OTH * WW) - (NTX * OTW));
                ty = rfli(ty + 1); oy = rfli(oy + OTH);
                if (ty == NTY) {
                    ty = 0; oy = 0;
                    zoff = rfli(zoff + (HH * WW));
                    off0 = zoff;
                }
            }
            if (tx == NTX - 1 || ty == NTY - 1) { ISSUE_EDGE(); } else { ISSUE_FAST(); }
        }

        // own ds_writes retired before own ds_reads; clobber pins ordering
        asm volatile("s_waitcnt lgkmcnt(0)" ::: "memory");

        // ---------- phase 2: horizontal conv + SSIM on OWN row ----------
        {
            f32x2 am[2][CPT];
            #pragma unroll
            for (int ch = 0; ch < 2; ++ch)
                #pragma unroll
                for (int j = 0; j < CPT; ++j) am[ch][j] = (f32x2){0.f, 0.f};

            #pragma unroll
            for (int ch = 0; ch < 2; ++ch) {
                #pragma unroll
                for (int t = 0; t < NPOS; ++t) {
                    f32x2 v = vbuf2[ch][c0 + t][rowl];   // max col 36+13=49=VW-1
                    #pragma unroll
                    for (int j = 0; j < CPT; ++j) {
                        int k = t - j;
                        if (k >= 0 && k < KS)        // folds at compile time
                            am[ch][j] += GW(k) * v;  // pk_fma
                    }
                }
            }

            const int orow = oyc + rowl;
            if (p2act && orow < HO) {
                #pragma unroll
                for (int j = 0; j < CPT; ++j) {
                    int ocol = oxc + c0 + j;
                    if (ocol < WO) {
                        f32x2 m = am[0][j], e = am[1][j];
                        f32x2 sq = m * m;                  // {mus^2, mud^2}
                        float A   = 0.5f * (sq.x - sq.y);  // 2*mu1*mu2
                        float Bm  = 0.5f * (sq.x + sq.y);  // mu1^2 + mu2^2
                        float S12 = 0.5f * (e.x - e.y) - A;   // 2*sigma12
                        float SS  = 0.5f * (e.x + e.y) - Bm;  // sig1^2 + sig2^2
                        float num = (A + c1) * (S12 + c2);
                        float den = (Bm + c1) * (SS + c2);
                        lsum += num * __builtin_amdgcn_rcpf(den);
                    }
                }
            }
        }
    }

    // ---------- reduction (single barrier, once per block) ----------
    #pragma unroll
    for (int off = 32; off; off >>= 1)
        lsum += __shfl_down(lsum, off, 64);
    if ((tid & 63) == 0) wsum[wv] = lsum;
    __syncthreads();
    if (tid == 0) {
        double tt = (double)wsum[0] + (double)wsum[1] +
                    (double)wsum[2] + (double)wsum[3];
        atomicAdd(acc, tt);
    }
}

__global__ void ssim_finalize(const double* __restrict__ acc,
                              float* __restrict__ out)
{
    out[0] = (float)(acc[0] / (double)(16LL * 3LL * (long long)HO * (long long)WO));
}

extern "C" void kernel_launch(void* const* d_in, const int* in_sizes, int n_in,
                              void* d_out, int out_size, void* d_ws, size_t ws_size,
                              hipStream_t stream) {
    const float* img1 = (const float*)d_in[0];
    const float* img2 = (const float*)d_in[1];
    const float* win  = (const float*)d_in[2];  // (3,1,11,11); channels identical
    float* out = (float*)d_out;
    double* acc = (double*)d_ws;

    hipMemsetAsync(acc, 0, sizeof(double), stream);

    ssim_sep_kernel<<<dim3(NBLK), 256, 0, stream>>>(img1, img2, win, acc);
    ssim_finalize<<<1, 1, 0, stream>>>(acc, out);
}